// Round 7
// baseline (354.710 us; speedup 1.0000x reference)
//
#include <hip/hip_runtime.h>
#include <cstdint>
#include <cstddef>

#define DIM    1024
#define DINNER 1024
#define DSTATE 2048
#define BSZ    8
#define TLEN   2048
#define MROWS  (BSZ * TLEN)   // 16384

typedef unsigned short u16;
typedef __attribute__((ext_vector_type(8))) __bf16 bf16x8;
typedef __attribute__((ext_vector_type(4))) float  f32x4;
typedef __attribute__((ext_vector_type(8))) u16    u16x8;

static __device__ __forceinline__ u16 f2bf(float f) {
  union { float f; uint32_t u; } v; v.f = f;
  uint32_t u = v.u;
  return (u16)((u + 0x7fffu + ((u >> 16) & 1u)) >> 16);  // RNE
}

static __device__ __forceinline__ float bf2f(u16 b) {
  union { uint32_t u; float f; } v; v.u = ((uint32_t)b) << 16;
  return v.f;
}

static __device__ __forceinline__ float silu(float x) {
  return x / (1.f + __expf(-x));
}

// ---------------- diagnostics ----------------
__global__ void sentinel(float* out) { out[0] = 12345.0f; }

// ---------------- elementwise ----------------

__global__ void cast_bf16x8(const float* __restrict__ in, u16* __restrict__ out, long n) {
  long i = ((long)blockIdx.x * blockDim.x + threadIdx.x) * 8;
  if (i >= n) return;
  float4 a = *(const float4*)(in + i);
  float4 b = *(const float4*)(in + i + 4);
  u16x8 o;
  o[0] = f2bf(a.x); o[1] = f2bf(a.y); o[2] = f2bf(a.z); o[3] = f2bf(a.w);
  o[4] = f2bf(b.x); o[5] = f2bf(b.y); o[6] = f2bf(b.z); o[7] = f2bf(b.w);
  *(u16x8*)(out + i) = o;
}

// in [R, C] f32 -> out [C, R] bf16
__global__ void transpose_cast(const float* __restrict__ in, u16* __restrict__ out,
                               int R, int C) {
  __shared__ float t[32][33];
  int c0 = blockIdx.x * 32, r0 = blockIdx.y * 32;
  int tx = threadIdx.x, ty = threadIdx.y;  // 32 x 8
#pragma unroll
  for (int i = 0; i < 32; i += 8)
    t[ty + i][tx] = in[(size_t)(r0 + ty + i) * C + c0 + tx];
  __syncthreads();
#pragma unroll
  for (int i = 0; i < 32; i += 8)
    out[(size_t)(c0 + ty + i) * R + r0 + tx] = f2bf(t[tx][ty + i]);
}

// ---------------- windowed-parallel scan (verified r6) ----------------

#define SEG  128
#define WARM 32

__global__ void __launch_bounds__(256) winscan(const u16* __restrict__ xB,
                                               u16* __restrict__ H,
                                               const float* __restrict__ h0,
                                               const float* __restrict__ logA,
                                               float* __restrict__ hf,
                                               int b0) {
  const int NSEG = TLEN / SEG;  // 16
  int tid  = blockIdx.x * 256 + threadIdx.x;
  int s    = tid & (DSTATE - 1);
  int rest = tid >> 11;
  int bl   = rest >> 4;
  int seg  = rest & (NSEG - 1);

  const float C2  = 2.8853900817779268f;  // 2*log2(e)
  const float L2E = 1.4426950408889634f;
  float A  = __builtin_amdgcn_rcpf(1.f + __builtin_amdgcn_exp2f(-logA[s] * L2E));
  float Ac = A * C2;

  const int t0 = seg * SEG;
  float h;
  const u16* src;
  if (seg == 0) {
    h = h0[(size_t)(b0 + bl) * DSTATE + s];
    src = xB + ((size_t)bl * TLEN) * DSTATE + s;
  } else {
    h = 0.f;
    src = xB + ((size_t)bl * TLEN + (t0 - WARM)) * DSTATE + s;
#pragma unroll
    for (int i = 0; i < WARM; ++i) {
      float g = fmaf(Ac, h, bf2f(src[(size_t)i * DSTATE]) * C2);
      float e = __builtin_amdgcn_exp2f(g);
      float r = __builtin_amdgcn_rcpf(e + 1.f);
      h = fmaf(-2.f, r, 1.f);
    }
    src += (size_t)WARM * DSTATE;
  }

  u16* dst = H + ((size_t)bl * TLEN + t0) * DSTATE + s;
  const int PF = 8;
  float buf[PF], nbuf[PF];
#pragma unroll
  for (int i = 0; i < PF; ++i) buf[i] = bf2f(src[(size_t)i * DSTATE]) * C2;
  for (int tc = 0; tc < SEG; tc += PF) {
    if (tc + PF < SEG) {
#pragma unroll
      for (int i = 0; i < PF; ++i) nbuf[i] = bf2f(src[(size_t)(tc + PF + i) * DSTATE]) * C2;
    }
#pragma unroll
    for (int i = 0; i < PF; ++i) {
      float g = fmaf(Ac, h, buf[i]);
      float e = __builtin_amdgcn_exp2f(g);
      float r = __builtin_amdgcn_rcpf(e + 1.f);
      h = fmaf(-2.f, r, 1.f);
      dst[(size_t)(tc + i) * DSTATE] = f2bf(h);
    }
#pragma unroll
    for (int i = 0; i < PF; ++i) buf[i] = nbuf[i];
  }
  if (seg == NSEG - 1) hf[(size_t)(b0 + bl) * DSTATE + s] = h;
}

// ---------------- 256x256 8-phase bf16 MFMA GEMM — 16-wave variant ----------------
// Same 8-phase ks-split double-buffered schedule as r4-r6 (race discipline unchanged);
// parameter change: 1024 threads = 16 waves (4x4), wave tile 64x64, acc[4][4] (64 AGPR)
// -> combined regs <= 128 -> 16 waves/CU (2x TLP to fill barrier/latency bubbles).
// STG = 1 global_load_lds per thread per half-tile; vmcnt gates re-derived: (3)/(3)/(0).

enum { EPI_F32 = 0, EPI_SILU_SPLIT = 1, EPI_BF16 = 2, EPI_MUL_SZ = 3 };

#define GBAR()  __builtin_amdgcn_s_barrier()
#define LGKM0() do { asm volatile("s_waitcnt lgkmcnt(0)" ::: "memory"); \
                     __builtin_amdgcn_sched_barrier(0); } while (0)

template <int EPI>
__global__ void __launch_bounds__(1024, 4) gemm256(const u16* __restrict__ A,
                                                   const u16* __restrict__ B,
                                                   float* __restrict__ Cf,
                                                   u16* __restrict__ O1,
                                                   u16* __restrict__ O2,
                                                   const u16* __restrict__ SZ,
                                                   int M, int N, int K) {
  extern __shared__ u16 lds[];   // 131072 B
  const int tid = threadIdx.x, wid = tid >> 6, lane = tid & 63;
  const int wm = wid >> 2, wn = wid & 3;   // 4 x 4 wave grid

  int bx = blockIdx.x, by = blockIdx.y;
  {
    int nwg = gridDim.x * gridDim.y;
    if ((nwg & 7) == 0) {
      int wg  = by * gridDim.x + bx;
      int swz = (wg & 7) * (nwg >> 3) + (wg >> 3);
      bx = swz % gridDim.x;
      by = swz / gridDim.x;
    }
  }
  const int m0 = bx * 256, n0 = by * 256;

  const int fr = lane & 15;
  const int kbs8 = ((lane >> 4) ^ ((fr >> 1) & 3)) * 8;   // swizzled frag k-offset (elems)
  const int srow = tid >> 2, skb = tid & 3;               // srow in [0,256): one pass covers tile

  f32x4 acc[4][4] = {};
  bf16x8 af[4], bfj[4];

  // stage one half-tile (16KB): 1 x global_load_lds(16B) per thread (1024 thr x 16B).
  auto STG = [&](int db, int mat, int ks, int kt) {
    int ksrc8 = (skb ^ ((srow >> 1) & 3)) * 8;            // inverse swizzle on global source
    const u16* P = mat ? B : A;
    const u16* g = P + (size_t)((mat ? n0 : m0) + srow) * K + (kt << 6) + (ks << 5) + ksrc8;
    u16* d = lds + (((db * 2 + mat) * 2 + ks) << 13) + (wid << 9);
    __builtin_amdgcn_global_load_lds((const __attribute__((address_space(1))) void*)g,
        (__attribute__((address_space(3))) void*)d, 16, 0, 0);
  };
  auto LDA = [&](int db, int ks) {
    const u16* base = lds + (((db * 2 + 0) * 2 + ks) << 13) + (wm * 64 + fr) * 32 + kbs8;
#pragma unroll
    for (int i = 0; i < 4; ++i) af[i] = *(const bf16x8*)(base + i * 512);
  };
  auto LDB2 = [&](int db, int ks, int jp) {
    const u16* base = lds + (((db * 2 + 1) * 2 + ks) << 13) + (wn * 64 + jp * 32 + fr) * 32 + kbs8;
#pragma unroll
    for (int j = 0; j < 2; ++j) bfj[jp * 2 + j] = *(const bf16x8*)(base + j * 512);
  };
  auto MM = [&](int jp) {
    __builtin_amdgcn_s_setprio(1);
#pragma unroll
    for (int i = 0; i < 4; ++i) {
      acc[i][jp * 2]     = __builtin_amdgcn_mfma_f32_16x16x32_bf16(af[i], bfj[jp * 2],     acc[i][jp * 2],     0, 0, 0);
      acc[i][jp * 2 + 1] = __builtin_amdgcn_mfma_f32_16x16x32_bf16(af[i], bfj[jp * 2 + 1], acc[i][jp * 2 + 1], 0, 0, 0);
    }
    __builtin_amdgcn_s_setprio(0);
  };

  const int T = K >> 6;   // K-tiles of 64
  const int I = T >> 1;   // iterations (2 K-tiles each)

  // prologue: tile0 -> db0 (4 half-tiles), tile1 -> db1 (A-ks0, B-ks0, A-ks1) = 7 loads.
  STG(0, 0, 0, 0); STG(0, 1, 0, 0); STG(0, 0, 1, 0); STG(0, 1, 1, 0);
  STG(1, 0, 0, 1); STG(1, 1, 0, 1); STG(1, 0, 1, 1);
  asm volatile("s_waitcnt vmcnt(3)" ::: "memory");   // oldest 4 = all of db0 landed
  GBAR();

  for (int it = 0; it < I; ++it) {
    const bool last = (it == I - 1);
    const int t1 = 2 * it + 1, t2 = 2 * it + 2, t3 = 2 * it + 3;

    // ph1: reads A[db0][ks0]+B[db0][ks0]j01; stages B[db1][ks1]<-t1 (freed prev ph8)
    LDA(0, 0); LDB2(0, 0, 0); STG(1, 1, 1, t1);
    GBAR(); LGKM0(); MM(0); GBAR();
    // ph2
    LDB2(0, 0, 1); if (!last) STG(0, 0, 0, t2);
    GBAR(); LGKM0(); MM(1); GBAR();
    // ph3
    LDA(0, 1); LDB2(0, 1, 0); if (!last) STG(0, 1, 0, t2);
    GBAR(); LGKM0(); MM(0); GBAR();
    // ph4: gate db1(t1): outstanding = prev{ph6,7,8} + ph1..ph4 = 7; leave ph2,3,4 -> vmcnt(3)
    LDB2(0, 1, 1); if (!last) STG(0, 0, 1, t2);
    if (last) { asm volatile("s_waitcnt vmcnt(0)" ::: "memory"); }
    else      { asm volatile("s_waitcnt vmcnt(3)" ::: "memory"); }
    GBAR(); LGKM0(); MM(1); GBAR();
    // ph5
    LDA(1, 0); LDB2(1, 0, 0); if (!last) STG(0, 1, 1, t2);
    GBAR(); LGKM0(); MM(0); GBAR();
    // ph6
    LDB2(1, 0, 1); if (!last) STG(1, 0, 0, t3);
    GBAR(); LGKM0(); MM(1); GBAR();
    // ph7
    LDA(1, 1); LDB2(1, 1, 0); if (!last) STG(1, 1, 0, t3);
    GBAR(); LGKM0(); MM(0); GBAR();
    // ph8: gate db0(t2): outstanding = ph2..ph8 = 7; leave ph6,7,8 -> vmcnt(3)
    LDB2(1, 1, 1); if (!last) { STG(1, 0, 1, t3); asm volatile("s_waitcnt vmcnt(3)" ::: "memory"); }
    GBAR(); LGKM0(); MM(1); GBAR();
  }

  // epilogue: C/D layout col=lane&15, row=(lane>>4)*4+reg   [m89/m91]
  const int cr = (lane >> 4) * 4;
  const int cc = lane & 15;
#pragma unroll
  for (int i = 0; i < 4; ++i)
#pragma unroll
    for (int j = 0; j < 4; ++j) {
      const int gm = m0 + wm * 64 + i * 16 + cr;
      const int gn = n0 + wn * 64 + j * 16 + cc;
#pragma unroll
      for (int r = 0; r < 4; ++r) {
        float v = acc[i][j][r];
        size_t idx = (size_t)(gm + r) * N + gn;
        if constexpr (EPI == EPI_F32) {
          Cf[idx] = v;
        } else if constexpr (EPI == EPI_BF16) {
          O1[idx] = f2bf(v);
        } else if constexpr (EPI == EPI_SILU_SPLIT) {
          u16 o = f2bf(silu(v));
          size_t half = (size_t)(gm + r) * (N / 2);
          if (gn < N / 2) O1[half + gn] = o;
          else            O2[half + gn - N / 2] = o;
        } else {  // EPI_MUL_SZ
          O1[idx] = f2bf(v * bf2f(SZ[idx]));
        }
      }
    }
}

// ---------------- launch ----------------

extern "C" void kernel_launch(void* const* d_in, const int* in_sizes, int n_in,
                              void* d_out, int out_size, void* d_ws, size_t ws_size,
                              hipStream_t stream) {
  const float* x     = (const float*)d_in[0];
  const float* h0    = (const float*)d_in[1];
  const float* W_in  = (const float*)d_in[2];
  const float* W_out = (const float*)d_in[3];
  const float* Bm    = (const float*)d_in[4];
  const float* Cm    = (const float*)d_in[5];
  const float* logA  = (const float*)d_in[6];
  float* out = (float*)d_out;                       // [16384, 1024] f32
  float* hf  = out + (size_t)MROWS * DIM;           // [8, 2048] f32

  const int LDSB = 131072;
  hipFuncSetAttribute((const void*)gemm256<EPI_F32>,        hipFuncAttributeMaxDynamicSharedMemorySize, LDSB);
  hipFuncSetAttribute((const void*)gemm256<EPI_SILU_SPLIT>, hipFuncAttributeMaxDynamicSharedMemorySize, LDSB);
  hipFuncSetAttribute((const void*)gemm256<EPI_BF16>,       hipFuncAttributeMaxDynamicSharedMemorySize, LDSB);
  hipFuncSetAttribute((const void*)gemm256<EPI_MUL_SZ>,     hipFuncAttributeMaxDynamicSharedMemorySize, LDSB);

  auto align256 = [](size_t b) { return (b + 255) & ~(size_t)255; };

  const size_t w_win  = align256((size_t)2 * DINNER * DIM * 2);
  const size_t w_wout = align256((size_t)DIM * DINNER * 2);
  const size_t w_bt   = align256((size_t)DSTATE * DINNER * 2);
  const size_t w_ct   = align256((size_t)DINNER * DSTATE * 2);
  const size_t w_weights = w_win + w_wout + w_bt + w_ct;

  int nb = 0;
  const int cand[4] = {8, 4, 2, 1};
  size_t su = 0, sx = 0, ssz = 0, sxb = 0;
  for (int ci = 0; ci < 4; ++ci) {
    int c = cand[ci];
    size_t Mc = (size_t)c * TLEN;
    su  = (size_t)Mc * DINNER * 2;   // u_bf
    sx  = (size_t)Mc * DINNER * 2;   // x_bf
    ssz = (size_t)Mc * DINNER * 2;   // sz_bf
    sxb = (size_t)Mc * DSTATE * 2;   // xB
    if (w_weights + su + sx + ssz + sxb <= ws_size) { nb = c; break; }
  }
  if (!nb) { sentinel<<<1, 1, 0, stream>>>(out); return; }

  char* ws = (char*)d_ws;
  u16* Win_bf  = (u16*)ws;             ws += w_win;
  u16* Wout_bf = (u16*)ws;             ws += w_wout;
  u16* BT_bf   = (u16*)ws;             ws += w_bt;
  u16* CT_bf   = (u16*)ws;             ws += w_ct;
  u16* u_bf    = (u16*)ws;             ws += su;    // H overlays [u_bf .. u_bf+su+sx)
  u16* x_bf    = (u16*)ws;             ws += sx;
  u16* sz_bf   = (u16*)ws;             ws += ssz;
  u16* xB_bf   = (u16*)ws;             ws += sxb;
  u16* H_bf    = u_bf;
  u16* y_bf    = xB_bf;

  cast_bf16x8<<<(2 * DINNER * DIM) / 8 / 256, 256, 0, stream>>>(W_in, Win_bf, (long)2 * DINNER * DIM);
  cast_bf16x8<<<(DIM * DINNER) / 8 / 256, 256, 0, stream>>>(W_out, Wout_bf, (long)DIM * DINNER);
  transpose_cast<<<dim3(DSTATE / 32, DINNER / 32), dim3(32, 8), 0, stream>>>(Bm, BT_bf, DINNER, DSTATE);
  transpose_cast<<<dim3(DINNER / 32, DSTATE / 32), dim3(32, 8), 0, stream>>>(Cm, CT_bf, DSTATE, DINNER);

  for (int b0 = 0; b0 < BSZ; b0 += nb) {
    const int Mc = nb * TLEN;
    const float* xc = x + (size_t)b0 * TLEN * DIM;
    float* outc = out + (size_t)b0 * TLEN * DIM;

    cast_bf16x8<<<((size_t)Mc * DIM) / 8 / 256, 256, 0, stream>>>(xc, x_bf, (long)Mc * DIM);

    // xz = x @ W_in^T, fused silu-split
    gemm256<EPI_SILU_SPLIT><<<dim3(Mc / 256, (2 * DINNER) / 256), 1024, LDSB, stream>>>(
        x_bf, Win_bf, nullptr, u_bf, sz_bf, nullptr, Mc, 2 * DINNER, DIM);

    // xB = u @ B_mat -> bf16
    gemm256<EPI_BF16><<<dim3(Mc / 256, DSTATE / 256), 1024, LDSB, stream>>>(
        u_bf, BT_bf, nullptr, xB_bf, nullptr, nullptr, Mc, DSTATE, DINNER);

    // windowed-parallel scan: xB -> H   (blocks = Mc*16/256 = Mc/16)
    winscan<<<Mc / 16, 256, 0, stream>>>(xB_bf, H_bf, h0, logA, hf, b0);

    // gy = H @ C_mat, fused * sz -> y_bf
    gemm256<EPI_MUL_SZ><<<dim3(Mc / 256, DINNER / 256), 1024, LDSB, stream>>>(
        H_bf, CT_bf, nullptr, y_bf, nullptr, sz_bf, Mc, DINNER, DSTATE);

    // out = y @ W_out^T  (f32)
    gemm256<EPI_F32><<<dim3(Mc / 256, DIM / 256), 1024, LDSB, stream>>>(
        y_bf, Wout_bf, outc, nullptr, nullptr, nullptr, Mc, DIM, DINNER);
  }
}

// Round 8
// 342.913 us; speedup vs baseline: 1.0344x; 1.0344x over previous
//
#include <hip/hip_runtime.h>
#include <cstdint>
#include <cstddef>

#define DIM    1024
#define DINNER 1024
#define DSTATE 2048
#define BSZ    8
#define TLEN   2048
#define MROWS  (BSZ * TLEN)   // 16384

typedef unsigned short u16;
typedef __attribute__((ext_vector_type(8))) __bf16 bf16x8;
typedef __attribute__((ext_vector_type(4))) float  f32x4;
typedef __attribute__((ext_vector_type(8))) u16    u16x8;

static __device__ __forceinline__ u16 f2bf(float f) {
  union { float f; uint32_t u; } v; v.f = f;
  uint32_t u = v.u;
  return (u16)((u + 0x7fffu + ((u >> 16) & 1u)) >> 16);  // RNE
}

static __device__ __forceinline__ float bf2f(u16 b) {
  union { uint32_t u; float f; } v; v.u = ((uint32_t)b) << 16;
  return v.f;
}

static __device__ __forceinline__ float silu(float x) {
  return x / (1.f + __expf(-x));
}

// ---------------- diagnostics ----------------
__global__ void sentinel(float* out) { out[0] = 12345.0f; }

// ---------------- elementwise ----------------

__global__ void cast_bf16x8(const float* __restrict__ in, u16* __restrict__ out, long n) {
  long i = ((long)blockIdx.x * blockDim.x + threadIdx.x) * 8;
  if (i >= n) return;
  float4 a = *(const float4*)(in + i);
  float4 b = *(const float4*)(in + i + 4);
  u16x8 o;
  o[0] = f2bf(a.x); o[1] = f2bf(a.y); o[2] = f2bf(a.z); o[3] = f2bf(a.w);
  o[4] = f2bf(b.x); o[5] = f2bf(b.y); o[6] = f2bf(b.z); o[7] = f2bf(b.w);
  *(u16x8*)(out + i) = o;
}

// in [R, C] f32 -> out [C, R] bf16
__global__ void transpose_cast(const float* __restrict__ in, u16* __restrict__ out,
                               int R, int C) {
  __shared__ float t[32][33];
  int c0 = blockIdx.x * 32, r0 = blockIdx.y * 32;
  int tx = threadIdx.x, ty = threadIdx.y;  // 32 x 8
#pragma unroll
  for (int i = 0; i < 32; i += 8)
    t[ty + i][tx] = in[(size_t)(r0 + ty + i) * C + c0 + tx];
  __syncthreads();
#pragma unroll
  for (int i = 0; i < 32; i += 8)
    out[(size_t)(c0 + ty + i) * R + r0 + tx] = f2bf(t[tx][ty + i]);
}

// ---------------- windowed-parallel scan (verified r6) ----------------

#define SEG  128
#define WARM 32

__global__ void __launch_bounds__(256) winscan(const u16* __restrict__ xB,
                                               u16* __restrict__ H,
                                               const float* __restrict__ h0,
                                               const float* __restrict__ logA,
                                               float* __restrict__ hf,
                                               int b0) {
  const int NSEG = TLEN / SEG;  // 16
  int tid  = blockIdx.x * 256 + threadIdx.x;
  int s    = tid & (DSTATE - 1);
  int rest = tid >> 11;
  int bl   = rest >> 4;
  int seg  = rest & (NSEG - 1);

  const float C2  = 2.8853900817779268f;  // 2*log2(e)
  const float L2E = 1.4426950408889634f;
  float A  = __builtin_amdgcn_rcpf(1.f + __builtin_amdgcn_exp2f(-logA[s] * L2E));
  float Ac = A * C2;

  const int t0 = seg * SEG;
  float h;
  const u16* src;
  if (seg == 0) {
    h = h0[(size_t)(b0 + bl) * DSTATE + s];
    src = xB + ((size_t)bl * TLEN) * DSTATE + s;
  } else {
    h = 0.f;
    src = xB + ((size_t)bl * TLEN + (t0 - WARM)) * DSTATE + s;
#pragma unroll
    for (int i = 0; i < WARM; ++i) {
      float g = fmaf(Ac, h, bf2f(src[(size_t)i * DSTATE]) * C2);
      float e = __builtin_amdgcn_exp2f(g);
      float r = __builtin_amdgcn_rcpf(e + 1.f);
      h = fmaf(-2.f, r, 1.f);
    }
    src += (size_t)WARM * DSTATE;
  }

  u16* dst = H + ((size_t)bl * TLEN + t0) * DSTATE + s;
  const int PF = 8;
  float buf[PF], nbuf[PF];
#pragma unroll
  for (int i = 0; i < PF; ++i) buf[i] = bf2f(src[(size_t)i * DSTATE]) * C2;
  for (int tc = 0; tc < SEG; tc += PF) {
    if (tc + PF < SEG) {
#pragma unroll
      for (int i = 0; i < PF; ++i) nbuf[i] = bf2f(src[(size_t)(tc + PF + i) * DSTATE]) * C2;
    }
#pragma unroll
    for (int i = 0; i < PF; ++i) {
      float g = fmaf(Ac, h, buf[i]);
      float e = __builtin_amdgcn_exp2f(g);
      float r = __builtin_amdgcn_rcpf(e + 1.f);
      h = fmaf(-2.f, r, 1.f);
      dst[(size_t)(tc + i) * DSTATE] = f2bf(h);
    }
#pragma unroll
    for (int i = 0; i < PF; ++i) buf[i] = nbuf[i];
  }
  if (seg == NSEG - 1) hf[(size_t)(b0 + bl) * DSTATE + s] = h;
}

// ---------------- 256x256 8-phase bf16 MFMA GEMM (r6 8-wave config) ----------------
// r8 changes vs r6 (loop/sync structure untouched):
//  (a) by-fast XCD chunking: an XCD's contiguous chunk shares few A panels + all of B
//      -> staging becomes L2-resident (attacks FETCH 141MB / stage-latency stalls).
//  (b) coalesced epilogue via per-wave LDS bounce: 16B stores + 16B SZ loads.

enum { EPI_F32 = 0, EPI_SILU_SPLIT = 1, EPI_BF16 = 2, EPI_MUL_SZ = 3 };

#define GBAR()  __builtin_amdgcn_s_barrier()
#define LGKM0() do { asm volatile("s_waitcnt lgkmcnt(0)" ::: "memory"); \
                     __builtin_amdgcn_sched_barrier(0); } while (0)

template <int EPI>
__global__ void __launch_bounds__(512, 2) gemm256(const u16* __restrict__ A,
                                                  const u16* __restrict__ B,
                                                  float* __restrict__ Cf,
                                                  u16* __restrict__ O1,
                                                  u16* __restrict__ O2,
                                                  const u16* __restrict__ SZ,
                                                  int M, int N, int K) {
  extern __shared__ u16 lds[];   // 131072 B
  const int tid = threadIdx.x, wid = tid >> 6, lane = tid & 63;
  const int wm = wid >> 2, wn = wid & 3;

  // by-fast XCD chunking: v enumerates (bx,by) with by FAST; XCD x owns a
  // contiguous v-range -> its resident blocks share ~gx/8 A panels + all B panels.
  int bx = blockIdx.x, by = blockIdx.y;
  {
    int gx = gridDim.x, gy = gridDim.y;
    int nwg = gx * gy;
    int wg  = blockIdx.y * gx + blockIdx.x;
    if ((nwg & 7) == 0) {
      int v = (wg & 7) * (nwg >> 3) + (wg >> 3);
      bx = v / gy;
      by = v - bx * gy;
    }
  }
  const int m0 = bx * 256, n0 = by * 256;

  const int fr = lane & 15;
  const int kbs8 = ((lane >> 4) ^ ((fr >> 1) & 3)) * 8;   // swizzled frag k-offset (elems)
  const int srow = tid >> 2, skb = tid & 3;

  f32x4 acc[8][4] = {};
  bf16x8 af[8], bfj[4];

  auto STG = [&](int db, int mat, int ks, int kt) {
#pragma unroll
    for (int c = 0; c < 2; ++c) {
      int row = c * 128 + srow;
      int ksrc8 = (skb ^ ((row >> 1) & 3)) * 8;
      const u16* P = mat ? B : A;
      const u16* g = P + (size_t)((mat ? n0 : m0) + row) * K + (kt << 6) + (ks << 5) + ksrc8;
      u16* d = lds + (((db * 2 + mat) * 2 + ks) << 13) + (c << 12) + (wid << 9);
      __builtin_amdgcn_global_load_lds((const __attribute__((address_space(1))) void*)g,
          (__attribute__((address_space(3))) void*)d, 16, 0, 0);
    }
  };
  auto LDA = [&](int db, int ks) {
    const u16* base = lds + (((db * 2 + 0) * 2 + ks) << 13) + (wm * 128 + fr) * 32 + kbs8;
#pragma unroll
    for (int i = 0; i < 8; ++i) af[i] = *(const bf16x8*)(base + i * 512);
  };
  auto LDB2 = [&](int db, int ks, int jp) {
    const u16* base = lds + (((db * 2 + 1) * 2 + ks) << 13) + (wn * 64 + jp * 32 + fr) * 32 + kbs8;
#pragma unroll
    for (int j = 0; j < 2; ++j) bfj[jp * 2 + j] = *(const bf16x8*)(base + j * 512);
  };
  auto MM = [&](int jp) {
    __builtin_amdgcn_s_setprio(1);
#pragma unroll
    for (int i = 0; i < 8; ++i) {
      acc[i][jp * 2]     = __builtin_amdgcn_mfma_f32_16x16x32_bf16(af[i], bfj[jp * 2],     acc[i][jp * 2],     0, 0, 0);
      acc[i][jp * 2 + 1] = __builtin_amdgcn_mfma_f32_16x16x32_bf16(af[i], bfj[jp * 2 + 1], acc[i][jp * 2 + 1], 0, 0, 0);
    }
    __builtin_amdgcn_s_setprio(0);
  };

  const int T = K >> 6;
  const int I = T >> 1;

  STG(0, 0, 0, 0); STG(0, 1, 0, 0); STG(0, 0, 1, 0); STG(0, 1, 1, 0);
  STG(1, 0, 0, 1); STG(1, 1, 0, 1); STG(1, 0, 1, 1);
  asm volatile("s_waitcnt vmcnt(6)" ::: "memory");
  GBAR();

  for (int it = 0; it < I; ++it) {
    const bool last = (it == I - 1);
    const int t1 = 2 * it + 1, t2 = 2 * it + 2, t3 = 2 * it + 3;

    LDA(0, 0); LDB2(0, 0, 0); STG(1, 1, 1, t1);
    GBAR(); LGKM0(); MM(0); GBAR();
    LDB2(0, 0, 1); if (!last) STG(0, 0, 0, t2);
    GBAR(); LGKM0(); MM(1); GBAR();
    LDA(0, 1); LDB2(0, 1, 0); if (!last) STG(0, 1, 0, t2);
    GBAR(); LGKM0(); MM(0); GBAR();
    LDB2(0, 1, 1); if (!last) STG(0, 0, 1, t2);
    if (last) { asm volatile("s_waitcnt vmcnt(0)" ::: "memory"); }
    else      { asm volatile("s_waitcnt vmcnt(6)" ::: "memory"); }
    GBAR(); LGKM0(); MM(1); GBAR();
    LDA(1, 0); LDB2(1, 0, 0); if (!last) STG(0, 1, 1, t2);
    GBAR(); LGKM0(); MM(0); GBAR();
    LDB2(1, 0, 1); if (!last) STG(1, 0, 0, t3);
    GBAR(); LGKM0(); MM(1); GBAR();
    LDA(1, 1); LDB2(1, 1, 0); if (!last) STG(1, 1, 0, t3);
    GBAR(); LGKM0(); MM(0); GBAR();
    LDB2(1, 1, 1); if (!last) { STG(1, 0, 1, t3); asm volatile("s_waitcnt vmcnt(6)" ::: "memory"); }
    GBAR(); LGKM0(); MM(1); GBAR();
  }

  // ---- coalesced epilogue via per-wave LDS bounce ----
  // Loop ended at GBAR -> all waves done reading LDS; each wave uses a private
  // 16x66 f32 slice (4-row stride 264 % 32banks spreads groups; ~2-way = free).
  // Per i: scatter acc (16 b32 writes) -> coalesced read (4 b128, one row/lane)
  // -> 16B global stores.  C/D frag layout col=lane&15, row=(lane>>4)*4+r [m89/m91].
  {
    float* esl = (float*)lds + wid * (16 * 66);
    const int cr = (lane >> 4) * 4;
    const int cc = lane & 15;
    const int erow = lane >> 2;         // 0..15
    const int ecol = (lane & 3) * 16;   // 0,16,32,48
#pragma unroll
    for (int i = 0; i < 8; ++i) {
#pragma unroll
      for (int j = 0; j < 4; ++j)
#pragma unroll
        for (int r = 0; r < 4; ++r)
          esl[(cr + r) * 66 + j * 16 + cc] = acc[i][j][r];
      asm volatile("s_waitcnt lgkmcnt(0)" ::: "memory");
      __builtin_amdgcn_sched_barrier(0);
      f32x4 v0 = *(const f32x4*)(esl + erow * 66 + ecol);
      f32x4 v1 = *(const f32x4*)(esl + erow * 66 + ecol + 4);
      f32x4 v2 = *(const f32x4*)(esl + erow * 66 + ecol + 8);
      f32x4 v3 = *(const f32x4*)(esl + erow * 66 + ecol + 12);
      asm volatile("s_waitcnt lgkmcnt(0)" ::: "memory");
      __builtin_amdgcn_sched_barrier(0);
      const int gm = m0 + wm * 128 + i * 16 + erow;
      const int gn = n0 + wn * 64 + ecol;
      if constexpr (EPI == EPI_F32) {
        float* cp = Cf + (size_t)gm * N + gn;
        *(f32x4*)(cp)      = v0;
        *(f32x4*)(cp + 4)  = v1;
        *(f32x4*)(cp + 8)  = v2;
        *(f32x4*)(cp + 12) = v3;
      } else if constexpr (EPI == EPI_BF16) {
        u16x8 o1, o2;
#pragma unroll
        for (int r = 0; r < 4; ++r) { o1[r] = f2bf(v0[r]); o1[4 + r] = f2bf(v1[r]); }
#pragma unroll
        for (int r = 0; r < 4; ++r) { o2[r] = f2bf(v2[r]); o2[4 + r] = f2bf(v3[r]); }
        u16* op = O1 + (size_t)gm * N + gn;
        *(u16x8*)(op) = o1;
        *(u16x8*)(op + 8) = o2;
      } else if constexpr (EPI == EPI_SILU_SPLIT) {
        u16x8 o1, o2;
#pragma unroll
        for (int r = 0; r < 4; ++r) { o1[r] = f2bf(silu(v0[r])); o1[4 + r] = f2bf(silu(v1[r])); }
#pragma unroll
        for (int r = 0; r < 4; ++r) { o2[r] = f2bf(silu(v2[r])); o2[4 + r] = f2bf(silu(v3[r])); }
        const int half = N >> 1;   // tile-uniform: n0 multiple of 256, half=1024
        u16* op = (gn < half ? O1 + (size_t)gm * half + gn
                             : O2 + (size_t)gm * half + (gn - half));
        *(u16x8*)(op) = o1;
        *(u16x8*)(op + 8) = o2;
      } else {  // EPI_MUL_SZ
        const u16* sp = SZ + (size_t)gm * N + gn;
        u16x8 s1 = *(const u16x8*)(sp);
        u16x8 s2 = *(const u16x8*)(sp + 8);
        u16x8 o1, o2;
#pragma unroll
        for (int r = 0; r < 4; ++r) { o1[r] = f2bf(v0[r] * bf2f(s1[r])); o1[4 + r] = f2bf(v1[r] * bf2f(s1[4 + r])); }
#pragma unroll
        for (int r = 0; r < 4; ++r) { o2[r] = f2bf(v2[r] * bf2f(s2[r])); o2[4 + r] = f2bf(v3[r] * bf2f(s2[4 + r])); }
        u16* op = O1 + (size_t)gm * N + gn;
        *(u16x8*)(op) = o1;
        *(u16x8*)(op + 8) = o2;
      }
    }
  }
}

// ---------------- launch ----------------

extern "C" void kernel_launch(void* const* d_in, const int* in_sizes, int n_in,
                              void* d_out, int out_size, void* d_ws, size_t ws_size,
                              hipStream_t stream) {
  const float* x     = (const float*)d_in[0];
  const float* h0    = (const float*)d_in[1];
  const float* W_in  = (const float*)d_in[2];
  const float* W_out = (const float*)d_in[3];
  const float* Bm    = (const float*)d_in[4];
  const float* Cm    = (const float*)d_in[5];
  const float* logA  = (const float*)d_in[6];
  float* out = (float*)d_out;                       // [16384, 1024] f32
  float* hf  = out + (size_t)MROWS * DIM;           // [8, 2048] f32

  const int LDSB = 131072;
  hipFuncSetAttribute((const void*)gemm256<EPI_F32>,        hipFuncAttributeMaxDynamicSharedMemorySize, LDSB);
  hipFuncSetAttribute((const void*)gemm256<EPI_SILU_SPLIT>, hipFuncAttributeMaxDynamicSharedMemorySize, LDSB);
  hipFuncSetAttribute((const void*)gemm256<EPI_BF16>,       hipFuncAttributeMaxDynamicSharedMemorySize, LDSB);
  hipFuncSetAttribute((const void*)gemm256<EPI_MUL_SZ>,     hipFuncAttributeMaxDynamicSharedMemorySize, LDSB);

  auto align256 = [](size_t b) { return (b + 255) & ~(size_t)255; };

  const size_t w_win  = align256((size_t)2 * DINNER * DIM * 2);
  const size_t w_wout = align256((size_t)DIM * DINNER * 2);
  const size_t w_bt   = align256((size_t)DSTATE * DINNER * 2);
  const size_t w_ct   = align256((size_t)DINNER * DSTATE * 2);
  const size_t w_weights = w_win + w_wout + w_bt + w_ct;

  int nb = 0;
  const int cand[4] = {8, 4, 2, 1};
  size_t su = 0, sx = 0, ssz = 0, sxb = 0;
  for (int ci = 0; ci < 4; ++ci) {
    int c = cand[ci];
    size_t Mc = (size_t)c * TLEN;
    su  = (size_t)Mc * DINNER * 2;   // u_bf
    sx  = (size_t)Mc * DINNER * 2;   // x_bf
    ssz = (size_t)Mc * DINNER * 2;   // sz_bf
    sxb = (size_t)Mc * DSTATE * 2;   // xB
    if (w_weights + su + sx + ssz + sxb <= ws_size) { nb = c; break; }
  }
  if (!nb) { sentinel<<<1, 1, 0, stream>>>(out); return; }

  char* ws = (char*)d_ws;
  u16* Win_bf  = (u16*)ws;             ws += w_win;
  u16* Wout_bf = (u16*)ws;             ws += w_wout;
  u16* BT_bf   = (u16*)ws;             ws += w_bt;
  u16* CT_bf   = (u16*)ws;             ws += w_ct;
  u16* u_bf    = (u16*)ws;             ws += su;    // H overlays [u_bf .. u_bf+su+sx)
  u16* x_bf    = (u16*)ws;             ws += sx;
  u16* sz_bf   = (u16*)ws;             ws += ssz;
  u16* xB_bf   = (u16*)ws;             ws += sxb;
  u16* H_bf    = u_bf;
  u16* y_bf    = xB_bf;

  cast_bf16x8<<<(2 * DINNER * DIM) / 8 / 256, 256, 0, stream>>>(W_in, Win_bf, (long)2 * DINNER * DIM);
  cast_bf16x8<<<(DIM * DINNER) / 8 / 256, 256, 0, stream>>>(W_out, Wout_bf, (long)DIM * DINNER);
  transpose_cast<<<dim3(DSTATE / 32, DINNER / 32), dim3(32, 8), 0, stream>>>(Bm, BT_bf, DINNER, DSTATE);
  transpose_cast<<<dim3(DINNER / 32, DSTATE / 32), dim3(32, 8), 0, stream>>>(Cm, CT_bf, DSTATE, DINNER);

  for (int b0 = 0; b0 < BSZ; b0 += nb) {
    const int Mc = nb * TLEN;
    const float* xc = x + (size_t)b0 * TLEN * DIM;
    float* outc = out + (size_t)b0 * TLEN * DIM;

    cast_bf16x8<<<((size_t)Mc * DIM) / 8 / 256, 256, 0, stream>>>(xc, x_bf, (long)Mc * DIM);

    // xz = x @ W_in^T, fused silu-split
    gemm256<EPI_SILU_SPLIT><<<dim3(Mc / 256, (2 * DINNER) / 256), 512, LDSB, stream>>>(
        x_bf, Win_bf, nullptr, u_bf, sz_bf, nullptr, Mc, 2 * DINNER, DIM);

    // xB = u @ B_mat -> bf16
    gemm256<EPI_BF16><<<dim3(Mc / 256, DSTATE / 256), 512, LDSB, stream>>>(
        u_bf, BT_bf, nullptr, xB_bf, nullptr, nullptr, Mc, DSTATE, DINNER);

    // windowed-parallel scan: xB -> H   (blocks = Mc*16/256 = Mc/16)
    winscan<<<Mc / 16, 256, 0, stream>>>(xB_bf, H_bf, h0, logA, hf, b0);

    // gy = H @ C_mat, fused * sz -> y_bf
    gemm256<EPI_MUL_SZ><<<dim3(Mc / 256, DINNER / 256), 512, LDSB, stream>>>(
        H_bf, CT_bf, nullptr, y_bf, nullptr, sz_bf, Mc, DINNER, DSTATE);

    // out = y @ W_out^T  (f32)
    gemm256<EPI_F32><<<dim3(Mc / 256, DIM / 256), 512, LDSB, stream>>>(
        y_bf, Wout_bf, outc, nullptr, nullptr, nullptr, Mc, DIM, DINNER);
  }
}

// Round 9
// 339.131 us; speedup vs baseline: 1.0459x; 1.0111x over previous
//
#include <hip/hip_runtime.h>
#include <cstdint>
#include <cstddef>

#define DIM    1024
#define DINNER 1024
#define DSTATE 2048
#define BSZ    8
#define TLEN   2048
#define MROWS  (BSZ * TLEN)   // 16384

typedef unsigned short u16;
typedef __attribute__((ext_vector_type(8))) __bf16 bf16x8;
typedef __attribute__((ext_vector_type(4))) float  f32x4;
typedef __attribute__((ext_vector_type(8))) u16    u16x8;

static __device__ __forceinline__ u16 f2bf(float f) {
  union { float f; uint32_t u; } v; v.f = f;
  uint32_t u = v.u;
  return (u16)((u + 0x7fffu + ((u >> 16) & 1u)) >> 16);  // RNE
}

static __device__ __forceinline__ float bf2f(u16 b) {
  union { uint32_t u; float f; } v; v.u = ((uint32_t)b) << 16;
  return v.f;
}

static __device__ __forceinline__ float silu(float x) {
  return x / (1.f + __expf(-x));
}

// ---------------- diagnostics ----------------
__global__ void sentinel(float* out) { out[0] = 12345.0f; }

// ---------------- elementwise ----------------

__global__ void cast_bf16x8(const float* __restrict__ in, u16* __restrict__ out, long n) {
  long i = ((long)blockIdx.x * blockDim.x + threadIdx.x) * 8;
  if (i >= n) return;
  float4 a = *(const float4*)(in + i);
  float4 b = *(const float4*)(in + i + 4);
  u16x8 o;
  o[0] = f2bf(a.x); o[1] = f2bf(a.y); o[2] = f2bf(a.z); o[3] = f2bf(a.w);
  o[4] = f2bf(b.x); o[5] = f2bf(b.y); o[6] = f2bf(b.z); o[7] = f2bf(b.w);
  *(u16x8*)(out + i) = o;
}

// in [R, C] f32 -> out [C, R] bf16
__global__ void transpose_cast(const float* __restrict__ in, u16* __restrict__ out,
                               int R, int C) {
  __shared__ float t[32][33];
  int c0 = blockIdx.x * 32, r0 = blockIdx.y * 32;
  int tx = threadIdx.x, ty = threadIdx.y;  // 32 x 8
#pragma unroll
  for (int i = 0; i < 32; i += 8)
    t[ty + i][tx] = in[(size_t)(r0 + ty + i) * C + c0 + tx];
  __syncthreads();
#pragma unroll
  for (int i = 0; i < 32; i += 8)
    out[(size_t)(c0 + ty + i) * R + r0 + tx] = f2bf(t[tx][ty + i]);
}

// ---------------- windowed-parallel scan (verified r6) ----------------

#define SEG  128
#define WARM 32

__global__ void __launch_bounds__(256) winscan(const u16* __restrict__ xB,
                                               u16* __restrict__ H,
                                               const float* __restrict__ h0,
                                               const float* __restrict__ logA,
                                               float* __restrict__ hf,
                                               int b0) {
  const int NSEG = TLEN / SEG;  // 16
  int tid  = blockIdx.x * 256 + threadIdx.x;
  int s    = tid & (DSTATE - 1);
  int rest = tid >> 11;
  int bl   = rest >> 4;
  int seg  = rest & (NSEG - 1);

  const float C2  = 2.8853900817779268f;  // 2*log2(e)
  const float L2E = 1.4426950408889634f;
  float A  = __builtin_amdgcn_rcpf(1.f + __builtin_amdgcn_exp2f(-logA[s] * L2E));
  float Ac = A * C2;

  const int t0 = seg * SEG;
  float h;
  const u16* src;
  if (seg == 0) {
    h = h0[(size_t)(b0 + bl) * DSTATE + s];
    src = xB + ((size_t)bl * TLEN) * DSTATE + s;
  } else {
    h = 0.f;
    src = xB + ((size_t)bl * TLEN + (t0 - WARM)) * DSTATE + s;
#pragma unroll
    for (int i = 0; i < WARM; ++i) {
      float g = fmaf(Ac, h, bf2f(src[(size_t)i * DSTATE]) * C2);
      float e = __builtin_amdgcn_exp2f(g);
      float r = __builtin_amdgcn_rcpf(e + 1.f);
      h = fmaf(-2.f, r, 1.f);
    }
    src += (size_t)WARM * DSTATE;
  }

  u16* dst = H + ((size_t)bl * TLEN + t0) * DSTATE + s;
  const int PF = 8;
  float buf[PF], nbuf[PF];
#pragma unroll
  for (int i = 0; i < PF; ++i) buf[i] = bf2f(src[(size_t)i * DSTATE]) * C2;
  for (int tc = 0; tc < SEG; tc += PF) {
    if (tc + PF < SEG) {
#pragma unroll
      for (int i = 0; i < PF; ++i) nbuf[i] = bf2f(src[(size_t)(tc + PF + i) * DSTATE]) * C2;
    }
#pragma unroll
    for (int i = 0; i < PF; ++i) {
      float g = fmaf(Ac, h, buf[i]);
      float e = __builtin_amdgcn_exp2f(g);
      float r = __builtin_amdgcn_rcpf(e + 1.f);
      h = fmaf(-2.f, r, 1.f);
      dst[(size_t)(tc + i) * DSTATE] = f2bf(h);
    }
#pragma unroll
    for (int i = 0; i < PF; ++i) buf[i] = nbuf[i];
  }
  if (seg == NSEG - 1) hf[(size_t)(b0 + bl) * DSTATE + s] = h;
}

// ---------------- 256x256 bf16 MFMA GEMM — 4-pair single-barrier schedule (r9) ----------------
// Same LDS map / stage order / vmcnt arithmetic as the verified r6 8-phase kernel; schedule
// surgery: ONE barrier per phase (at phase start) and all reads merged into odd phases.
//
// Safety invariant (1 barrier/phase): wave enters phase p+1 only after ALL waves finished
// phase p's body; each wave drains lgkmcnt(0) BEFORE its MM0, so every LDS read of a region
// has RETURNED (data in regs) before any wave's later-phase STG can overwrite that region.
// Per-region check (stage happens >=2 phases after last read-issue, with full drain between):
//   B[1][1]<-t1 @odd1 : read prev-iter odd4 (drained before prev MM0)        OK
//   A[0][0]<-t2 @even1: read odd1 (drained odd1)                             OK
//   B[0][0]<-t2 @odd2 : read odd1 (drained odd1)                             OK
//   A[0][1]<-t2 @even2: read odd2 (drained odd2)                             OK
//   B[0][1]<-t2 @odd3 : read odd2 (drained odd2)                             OK
//   A[1][0]<-t3 @even3: read odd3 (drained odd3)                             OK
//   B[1][0]<-t3 @odd4 : read odd3 (drained odd3)                             OK
//   A[1][1]<-t3 @even4: read odd4 (drained odd4)                             OK
// vmcnt: pair2-even gate db1(t1): outstanding = prev{e3,o4,e4}(6) + {o1,e1,o2,e2}(8)=14,
//   need oldest 8 landed -> vmcnt(6).  pair4-even gate db0(t2): leave {e3,o4,e4}=6 -> vmcnt(6).
//   Last iter: vmcnt(0) at pair2 (nothing staged after o1).  Each STG = 2 loads.

enum { EPI_F32 = 0, EPI_SILU_SPLIT = 1, EPI_BF16 = 2, EPI_MUL_SZ = 3 };

#define GBAR()  __builtin_amdgcn_s_barrier()
#define LGKM0() do { asm volatile("s_waitcnt lgkmcnt(0)" ::: "memory"); \
                     __builtin_amdgcn_sched_barrier(0); } while (0)

template <int EPI>
__global__ void __launch_bounds__(512, 2) gemm256(const u16* __restrict__ A,
                                                  const u16* __restrict__ B,
                                                  float* __restrict__ Cf,
                                                  u16* __restrict__ O1,
                                                  u16* __restrict__ O2,
                                                  const u16* __restrict__ SZ,
                                                  int M, int N, int K) {
  extern __shared__ u16 lds[];   // 131072 B
  const int tid = threadIdx.x, wid = tid >> 6, lane = tid & 63;
  const int wm = wid >> 2, wn = wid & 3;

  // by-fast XCD chunking (r8): keeps staging L2-resident.
  int bx = blockIdx.x, by = blockIdx.y;
  {
    int gx = gridDim.x, gy = gridDim.y;
    int nwg = gx * gy;
    int wg  = blockIdx.y * gx + blockIdx.x;
    if ((nwg & 7) == 0) {
      int v = (wg & 7) * (nwg >> 3) + (wg >> 3);
      bx = v / gy;
      by = v - bx * gy;
    }
  }
  const int m0 = bx * 256, n0 = by * 256;

  const int fr = lane & 15;
  const int kbs8 = ((lane >> 4) ^ ((fr >> 1) & 3)) * 8;   // swizzled frag k-offset (elems)
  const int srow = tid >> 2, skb = tid & 3;

  f32x4 acc[8][4] = {};
  bf16x8 af[8], bfj[4];

  auto STG = [&](int db, int mat, int ks, int kt) {
#pragma unroll
    for (int c = 0; c < 2; ++c) {
      int row = c * 128 + srow;
      int ksrc8 = (skb ^ ((row >> 1) & 3)) * 8;
      const u16* P = mat ? B : A;
      const u16* g = P + (size_t)((mat ? n0 : m0) + row) * K + (kt << 6) + (ks << 5) + ksrc8;
      u16* d = lds + (((db * 2 + mat) * 2 + ks) << 13) + (c << 12) + (wid << 9);
      __builtin_amdgcn_global_load_lds((const __attribute__((address_space(1))) void*)g,
          (__attribute__((address_space(3))) void*)d, 16, 0, 0);
    }
  };
  auto LDA = [&](int db, int ks) {
    const u16* base = lds + (((db * 2 + 0) * 2 + ks) << 13) + (wm * 128 + fr) * 32 + kbs8;
#pragma unroll
    for (int i = 0; i < 8; ++i) af[i] = *(const bf16x8*)(base + i * 512);
  };
  auto LDB4 = [&](int db, int ks) {
    const u16* base = lds + (((db * 2 + 1) * 2 + ks) << 13) + (wn * 64 + fr) * 32 + kbs8;
#pragma unroll
    for (int j = 0; j < 4; ++j) bfj[j] = *(const bf16x8*)(base + j * 512);
  };
  auto MM = [&](int jp) {
    __builtin_amdgcn_s_setprio(1);
#pragma unroll
    for (int i = 0; i < 8; ++i) {
      acc[i][jp * 2]     = __builtin_amdgcn_mfma_f32_16x16x32_bf16(af[i], bfj[jp * 2],     acc[i][jp * 2],     0, 0, 0);
      acc[i][jp * 2 + 1] = __builtin_amdgcn_mfma_f32_16x16x32_bf16(af[i], bfj[jp * 2 + 1], acc[i][jp * 2 + 1], 0, 0, 0);
    }
    __builtin_amdgcn_s_setprio(0);
  };

  const int T = K >> 6;
  const int I = T >> 1;

  // prologue: tile0 -> db0 (4 half-tiles), tile1 -> db1 (A-ks0, B-ks0, A-ks1). 14 loads.
  STG(0, 0, 0, 0); STG(0, 1, 0, 0); STG(0, 0, 1, 0); STG(0, 1, 1, 0);
  STG(1, 0, 0, 1); STG(1, 1, 0, 1); STG(1, 0, 1, 1);
  asm volatile("s_waitcnt vmcnt(6)" ::: "memory");   // all of db0 landed

  for (int it = 0; it < I; ++it) {
    const bool last = (it == I - 1);
    const int t1 = 2 * it + 1, t2 = 2 * it + 2, t3 = 2 * it + 3;

    // pair1 odd: reads db0ks0 (A + all B); stage B[1][1]<-t1
    GBAR(); STG(1, 1, 1, t1); LDA(0, 0); LDB4(0, 0);
    LGKM0(); MM(0);
    // pair1 even: stage A[0][0]<-t2; MM1 (no wait — operands already in regs)
    GBAR(); if (!last) STG(0, 0, 0, t2); MM(1);

    // pair2 odd: reads db0ks1; stage B[0][0]<-t2
    GBAR(); if (!last) STG(0, 1, 0, t2); LDA(0, 1); LDB4(0, 1);
    LGKM0(); MM(0);
    // pair2 even: stage A[0][1]<-t2; vmcnt gate for db1(t1) before pair3 reads
    GBAR(); if (!last) STG(0, 0, 1, t2);
    if (last) { asm volatile("s_waitcnt vmcnt(0)" ::: "memory"); }
    else      { asm volatile("s_waitcnt vmcnt(6)" ::: "memory"); }
    MM(1);

    // pair3 odd: reads db1ks0; stage B[0][1]<-t2
    GBAR(); if (!last) STG(0, 1, 1, t2); LDA(1, 0); LDB4(1, 0);
    LGKM0(); MM(0);
    // pair3 even: stage A[1][0]<-t3
    GBAR(); if (!last) STG(1, 0, 0, t3); MM(1);

    // pair4 odd: reads db1ks1; stage B[1][0]<-t3
    GBAR(); if (!last) STG(1, 1, 0, t3); LDA(1, 1); LDB4(1, 1);
    LGKM0(); MM(0);
    // pair4 even: stage A[1][1]<-t3; vmcnt gate for db0(t2) before next-iter pair1
    GBAR();
    if (!last) { STG(1, 0, 1, t3); asm volatile("s_waitcnt vmcnt(6)" ::: "memory"); }
    MM(1);
  }
  GBAR();   // protect epilogue LDS bounce from other waves' loop reads

  // ---- coalesced epilogue via per-wave LDS bounce (r8) ----
  {
    float* esl = (float*)lds + wid * (16 * 66);
    const int cr = (lane >> 4) * 4;
    const int cc = lane & 15;
    const int erow = lane >> 2;         // 0..15
    const int ecol = (lane & 3) * 16;   // 0,16,32,48
#pragma unroll
    for (int i = 0; i < 8; ++i) {
#pragma unroll
      for (int j = 0; j < 4; ++j)
#pragma unroll
        for (int r = 0; r < 4; ++r)
          esl[(cr + r) * 66 + j * 16 + cc] = acc[i][j][r];
      asm volatile("s_waitcnt lgkmcnt(0)" ::: "memory");
      __builtin_amdgcn_sched_barrier(0);
      f32x4 v0 = *(const f32x4*)(esl + erow * 66 + ecol);
      f32x4 v1 = *(const f32x4*)(esl + erow * 66 + ecol + 4);
      f32x4 v2 = *(const f32x4*)(esl + erow * 66 + ecol + 8);
      f32x4 v3 = *(const f32x4*)(esl + erow * 66 + ecol + 12);
      asm volatile("s_waitcnt lgkmcnt(0)" ::: "memory");
      __builtin_amdgcn_sched_barrier(0);
      const int gm = m0 + wm * 128 + i * 16 + erow;
      const int gn = n0 + wn * 64 + ecol;
      if constexpr (EPI == EPI_F32) {
        float* cp = Cf + (size_t)gm * N + gn;
        *(f32x4*)(cp)      = v0;
        *(f32x4*)(cp + 4)  = v1;
        *(f32x4*)(cp + 8)  = v2;
        *(f32x4*)(cp + 12) = v3;
      } else if constexpr (EPI == EPI_BF16) {
        u16x8 o1, o2;
#pragma unroll
        for (int r = 0; r < 4; ++r) { o1[r] = f2bf(v0[r]); o1[4 + r] = f2bf(v1[r]); }
#pragma unroll
        for (int r = 0; r < 4; ++r) { o2[r] = f2bf(v2[r]); o2[4 + r] = f2bf(v3[r]); }
        u16* op = O1 + (size_t)gm * N + gn;
        *(u16x8*)(op) = o1;
        *(u16x8*)(op + 8) = o2;
      } else if constexpr (EPI == EPI_SILU_SPLIT) {
        u16x8 o1, o2;
#pragma unroll
        for (int r = 0; r < 4; ++r) { o1[r] = f2bf(silu(v0[r])); o1[4 + r] = f2bf(silu(v1[r])); }
#pragma unroll
        for (int r = 0; r < 4; ++r) { o2[r] = f2bf(silu(v2[r])); o2[4 + r] = f2bf(silu(v3[r])); }
        const int half = N >> 1;
        u16* op = (gn < half ? O1 + (size_t)gm * half + gn
                             : O2 + (size_t)gm * half + (gn - half));
        *(u16x8*)(op) = o1;
        *(u16x8*)(op + 8) = o2;
      } else {  // EPI_MUL_SZ
        const u16* sp = SZ + (size_t)gm * N + gn;
        u16x8 s1 = *(const u16x8*)(sp);
        u16x8 s2 = *(const u16x8*)(sp + 8);
        u16x8 o1, o2;
#pragma unroll
        for (int r = 0; r < 4; ++r) { o1[r] = f2bf(v0[r] * bf2f(s1[r])); o1[4 + r] = f2bf(v1[r] * bf2f(s1[4 + r])); }
#pragma unroll
        for (int r = 0; r < 4; ++r) { o2[r] = f2bf(v2[r] * bf2f(s2[r])); o2[4 + r] = f2bf(v3[r] * bf2f(s2[4 + r])); }
        u16* op = O1 + (size_t)gm * N + gn;
        *(u16x8*)(op) = o1;
        *(u16x8*)(op + 8) = o2;
      }
    }
  }
}

// ---------------- launch ----------------

extern "C" void kernel_launch(void* const* d_in, const int* in_sizes, int n_in,
                              void* d_out, int out_size, void* d_ws, size_t ws_size,
                              hipStream_t stream) {
  const float* x     = (const float*)d_in[0];
  const float* h0    = (const float*)d_in[1];
  const float* W_in  = (const float*)d_in[2];
  const float* W_out = (const float*)d_in[3];
  const float* Bm    = (const float*)d_in[4];
  const float* Cm    = (const float*)d_in[5];
  const float* logA  = (const float*)d_in[6];
  float* out = (float*)d_out;                       // [16384, 1024] f32
  float* hf  = out + (size_t)MROWS * DIM;           // [8, 2048] f32

  const int LDSB = 131072;
  hipFuncSetAttribute((const void*)gemm256<EPI_F32>,        hipFuncAttributeMaxDynamicSharedMemorySize, LDSB);
  hipFuncSetAttribute((const void*)gemm256<EPI_SILU_SPLIT>, hipFuncAttributeMaxDynamicSharedMemorySize, LDSB);
  hipFuncSetAttribute((const void*)gemm256<EPI_BF16>,       hipFuncAttributeMaxDynamicSharedMemorySize, LDSB);
  hipFuncSetAttribute((const void*)gemm256<EPI_MUL_SZ>,     hipFuncAttributeMaxDynamicSharedMemorySize, LDSB);

  auto align256 = [](size_t b) { return (b + 255) & ~(size_t)255; };

  const size_t w_win  = align256((size_t)2 * DINNER * DIM * 2);
  const size_t w_wout = align256((size_t)DIM * DINNER * 2);
  const size_t w_bt   = align256((size_t)DSTATE * DINNER * 2);
  const size_t w_ct   = align256((size_t)DINNER * DSTATE * 2);
  const size_t w_weights = w_win + w_wout + w_bt + w_ct;

  int nb = 0;
  const int cand[4] = {8, 4, 2, 1};
  size_t su = 0, sx = 0, ssz = 0, sxb = 0;
  for (int ci = 0; ci < 4; ++ci) {
    int c = cand[ci];
    size_t Mc = (size_t)c * TLEN;
    su  = (size_t)Mc * DINNER * 2;   // u_bf
    sx  = (size_t)Mc * DINNER * 2;   // x_bf
    ssz = (size_t)Mc * DINNER * 2;   // sz_bf
    sxb = (size_t)Mc * DSTATE * 2;   // xB
    if (w_weights + su + sx + ssz + sxb <= ws_size) { nb = c; break; }
  }
  if (!nb) { sentinel<<<1, 1, 0, stream>>>(out); return; }

  char* ws = (char*)d_ws;
  u16* Win_bf  = (u16*)ws;             ws += w_win;
  u16* Wout_bf = (u16*)ws;             ws += w_wout;
  u16* BT_bf   = (u16*)ws;             ws += w_bt;
  u16* CT_bf   = (u16*)ws;             ws += w_ct;
  u16* u_bf    = (u16*)ws;             ws += su;    // H overlays [u_bf .. u_bf+su+sx)
  u16* x_bf    = (u16*)ws;             ws += sx;
  u16* sz_bf   = (u16*)ws;             ws += ssz;
  u16* xB_bf   = (u16*)ws;             ws += sxb;
  u16* H_bf    = u_bf;
  u16* y_bf    = xB_bf;

  cast_bf16x8<<<(2 * DINNER * DIM) / 8 / 256, 256, 0, stream>>>(W_in, Win_bf, (long)2 * DINNER * DIM);
  cast_bf16x8<<<(DIM * DINNER) / 8 / 256, 256, 0, stream>>>(W_out, Wout_bf, (long)DIM * DINNER);
  transpose_cast<<<dim3(DSTATE / 32, DINNER / 32), dim3(32, 8), 0, stream>>>(Bm, BT_bf, DINNER, DSTATE);
  transpose_cast<<<dim3(DINNER / 32, DSTATE / 32), dim3(32, 8), 0, stream>>>(Cm, CT_bf, DSTATE, DINNER);

  for (int b0 = 0; b0 < BSZ; b0 += nb) {
    const int Mc = nb * TLEN;
    const float* xc = x + (size_t)b0 * TLEN * DIM;
    float* outc = out + (size_t)b0 * TLEN * DIM;

    cast_bf16x8<<<((size_t)Mc * DIM) / 8 / 256, 256, 0, stream>>>(xc, x_bf, (long)Mc * DIM);

    // xz = x @ W_in^T, fused silu-split
    gemm256<EPI_SILU_SPLIT><<<dim3(Mc / 256, (2 * DINNER) / 256), 512, LDSB, stream>>>(
        x_bf, Win_bf, nullptr, u_bf, sz_bf, nullptr, Mc, 2 * DINNER, DIM);

    // xB = u @ B_mat -> bf16
    gemm256<EPI_BF16><<<dim3(Mc / 256, DSTATE / 256), 512, LDSB, stream>>>(
        u_bf, BT_bf, nullptr, xB_bf, nullptr, nullptr, Mc, DSTATE, DINNER);

    // windowed-parallel scan: xB -> H   (blocks = Mc*16/256 = Mc/16)
    winscan<<<Mc / 16, 256, 0, stream>>>(xB_bf, H_bf, h0, logA, hf, b0);

    // gy = H @ C_mat, fused * sz -> y_bf
    gemm256<EPI_MUL_SZ><<<dim3(Mc / 256, DINNER / 256), 512, LDSB, stream>>>(
        H_bf, CT_bf, nullptr, y_bf, nullptr, sz_bf, Mc, DINNER, DSTATE);

    // out = y @ W_out^T  (f32)
    gemm256<EPI_F32><<<dim3(Mc / 256, DIM / 256), 512, LDSB, stream>>>(
        y_bf, Wout_bf, outc, nullptr, nullptr, nullptr, Mc, DIM, DINNER);
  }
}